// Round 1
// baseline (832.852 us; speedup 1.0000x reference)
//
#include <hip/hip_runtime.h>
#include <math.h>

#define NCLS  20
#define MSZ   512
#define DIM   256
#define HW    16384      // 128*128
#define NPIX  131072     // 4 * 2 * 16384
#define AROWS 10240      // NCLS * MSZ
#define TEMP_INV 10.0f

// ---------------- K1: labels from nearest-resized gt ----------------
__global__ __launch_bounds__(256) void k_labels(const int* __restrict__ mg,
                                                const int* __restrict__ ag,
                                                int* __restrict__ labels) {
    int n = blockIdx.x * 256 + threadIdx.x;           // n < NPIX
    int b = n >> 15;                                   // /32768
    int r = n & 32767;
    const int* g = (r < HW) ? mg : ag;
    int p = (r < HW) ? r : (r - HW);
    int h = p >> 7, w = p & 127;
    int lab = g[(((size_t)b * 512) + (size_t)(h << 2)) * 512 + (size_t)(w << 2)];
    if (lab == 255) lab = -1;           // ignore
    else if (lab == 254) lab = NCLS - 1;
    labels[n] = lab;
}

// ---------------- K2: ordered per-class selection (first MSZ indices) ----------------
__global__ __launch_bounds__(256) void k_select(const int* __restrict__ labels,
                                                int* __restrict__ sel_idx,
                                                int* __restrict__ counts) {
    int c = blockIdx.x;
    int t = threadIdx.x;
    int lane = t & 63, wv = t >> 6;
    __shared__ int wcnt[4];
    int base = 0;
    for (int chunk = 0; chunk < NPIX; chunk += 256) {
        int n = chunk + t;
        bool match = (labels[n] == c);
        unsigned long long mask = __ballot(match);
        if (lane == 0) wcnt[wv] = __popcll(mask);
        __syncthreads();
        int prefix = 0;
#pragma unroll
        for (int i = 0; i < 4; ++i) if (i < wv) prefix += wcnt[i];
        int tot = wcnt[0] + wcnt[1] + wcnt[2] + wcnt[3];
        int rank = base + prefix + __popcll(mask & ((1ull << lane) - 1ull));
        if (match && rank < MSZ) sel_idx[c * MSZ + rank] = n;
        base += tot;
        __syncthreads();
        if (base >= MSZ) break;
    }
    if (t == 0) counts[c] = base;  // capped semantics OK: only used as (m < counts)
    // fill remainder with pixel 0 (provably unused: masked out of bank update & loss)
    for (int r = base + t; r < MSZ; r += 256) sel_idx[c * MSZ + r] = 0;
}

// block-wide sum over 256 threads (4 waves)
__device__ __forceinline__ float blockReduceSum256(float v, float* sh4) {
    int t = threadIdx.x;
#pragma unroll
    for (int off = 32; off > 0; off >>= 1) v += __shfl_down(v, off, 64);
    if ((t & 63) == 0) sh4[t >> 6] = v;
    __syncthreads();
    float tot = sh4[0] + sh4[1] + sh4[2] + sh4[3];
    __syncthreads();
    return tot;
}

// ---------------- K3: gather selected pixels + L2 normalize -> anchors ----------------
__global__ __launch_bounds__(256) void k_gather(const float* __restrict__ mainp,
                                                const float* __restrict__ auxp,
                                                const int* __restrict__ sel_idx,
                                                float* __restrict__ anchors) {
    __shared__ float sh4[4];
    int a = blockIdx.x;          // 0..AROWS-1
    int t = threadIdx.x;         // channel
    int n = sel_idx[a];
    int b = n >> 15, r = n & 32767;
    const float* src = (r < HW) ? mainp : auxp;
    int p = (r < HW) ? r : (r - HW);
    float x = src[(size_t)b * DIM * HW + (size_t)t * HW + (size_t)p];
    float ss = blockReduceSum256(x * x, sh4);
    float scale = 1.0f / fmaxf(sqrtf(ss), 1e-12f);
    anchors[(size_t)a * DIM + t] = x * scale;
}

// ---------------- K4: momentum bank update + renorm -> contras, c_valid ----------------
__global__ __launch_bounds__(256) void k_bank(const float* __restrict__ bank,
                                              const float* __restrict__ anchors,
                                              const int* __restrict__ counts,
                                              float* __restrict__ contras,
                                              int* __restrict__ c_valid) {
    __shared__ float sh4[4];
    int a = blockIdx.x;
    int t = threadIdx.x;
    int c = a >> 9, m = a & 511;
    size_t idx = (size_t)a * DIM + t;
    float bv = bank[idx];
    bool upd = m < counts[c];
    float u = upd ? (0.999f * bv + 0.001f * anchors[idx]) : bv;
    float ss = blockReduceSum256(u * u, sh4);
    float nrm = sqrtf(ss);
    float outv = upd ? (u / fmaxf(nrm, 1e-12f)) : bv;
    contras[idx] = outv;
    if (t == 0) c_valid[a] = (nrm > 0.0f) ? 1 : 0;
}

// ---------------- K5: fused scores + softmax statistics ----------------
// 128x128 tile per block, K=256, fp32 vector FMA. Accumulate per-row
// sum(exp(s)) over valid cols and sum(s) over positive cols via atomics.
#define TS 128
#define BK 16
__global__ __launch_bounds__(256) void k_score(const float* __restrict__ A,
                                               const float* __restrict__ Bc,
                                               const int* __restrict__ c_valid,
                                               float* __restrict__ row_sumexp,
                                               float* __restrict__ row_pos_sum) {
    __shared__ float As[BK][TS + 4];
    __shared__ float Bs[BK][TS + 4];
    int t = threadIdx.x;
    int tx = t & 15, ty = t >> 4;
    int row0 = blockIdx.x * TS, col0 = blockIdx.y * TS;

    float acc[8][8];
#pragma unroll
    for (int i = 0; i < 8; ++i)
#pragma unroll
        for (int j = 0; j < 8; ++j) acc[i][j] = 0.0f;

    for (int k0 = 0; k0 < DIM; k0 += BK) {
#pragma unroll
        for (int l = 0; l < 2; ++l) {
            int f4 = t + l * 256;           // 0..511
            int row = f4 >> 2, kr = f4 & 3;
            float4 va = *(const float4*)(A + (size_t)(row0 + row) * DIM + k0 + kr * 4);
            As[kr * 4 + 0][row] = va.x;
            As[kr * 4 + 1][row] = va.y;
            As[kr * 4 + 2][row] = va.z;
            As[kr * 4 + 3][row] = va.w;
            float4 vb = *(const float4*)(Bc + (size_t)(col0 + row) * DIM + k0 + kr * 4);
            Bs[kr * 4 + 0][row] = vb.x;
            Bs[kr * 4 + 1][row] = vb.y;
            Bs[kr * 4 + 2][row] = vb.z;
            Bs[kr * 4 + 3][row] = vb.w;
        }
        __syncthreads();
#pragma unroll
        for (int kk = 0; kk < BK; ++kk) {
            float a[8], b[8];
            *(float4*)&a[0] = *(const float4*)&As[kk][ty * 8];
            *(float4*)&a[4] = *(const float4*)&As[kk][ty * 8 + 4];
            *(float4*)&b[0] = *(const float4*)&Bs[kk][tx * 8];
            *(float4*)&b[4] = *(const float4*)&Bs[kk][tx * 8 + 4];
#pragma unroll
            for (int i = 0; i < 8; ++i)
#pragma unroll
                for (int j = 0; j < 8; ++j) acc[i][j] += a[i] * b[j];
        }
        __syncthreads();
    }

    // class blocks are 512 wide; TS=128 divides 512 -> uniform per tile
    bool same = (row0 >> 9) == (col0 >> 9);
    int cvv[8];
#pragma unroll
    for (int j = 0; j < 8; ++j) cvv[j] = c_valid[col0 + tx * 8 + j];

    float es[8], ps[8];
#pragma unroll
    for (int i = 0; i < 8; ++i) {
        float e = 0.0f, pp = 0.0f;
#pragma unroll
        for (int j = 0; j < 8; ++j) {
            float s = acc[i][j] * TEMP_INV;     // |s| <= ~10, exp never overflows
            if (cvv[j]) { e += expf(s); pp += s; }
        }
        es[i] = e; ps[i] = pp;
    }

    // reduce across the 16 tx-threads per row, reusing the LDS tiles
    float* red_e = &As[0][0];   // 2112 floats >= 128*16
    float* red_p = &Bs[0][0];
#pragma unroll
    for (int i = 0; i < 8; ++i) {
        red_e[(ty * 8 + i) * 16 + tx] = es[i];
        red_p[(ty * 8 + i) * 16 + tx] = ps[i];
    }
    __syncthreads();
    if (t < TS) {
        float se = 0.0f, sp = 0.0f;
#pragma unroll
        for (int x = 0; x < 16; ++x) { se += red_e[t * 16 + x]; sp += red_p[t * 16 + x]; }
        atomicAdd(&row_sumexp[row0 + t], se);
        if (same) atomicAdd(&row_pos_sum[row0 + t], sp);
    }
}

// ---------------- K6: final loss ----------------
__global__ __launch_bounds__(256) void k_final(const float* __restrict__ row_sumexp,
                                               const float* __restrict__ row_pos_sum,
                                               const int* __restrict__ c_valid,
                                               const int* __restrict__ counts,
                                               float* __restrict__ out) {
    __shared__ int pcnt[NCLS];
    __shared__ float sred[4];
    __shared__ int cred[4];
    int t = threadIdx.x;
    if (t < NCLS) {
        int s = 0;
        for (int m = 0; m < MSZ; ++m) s += c_valid[t * MSZ + m];
        pcnt[t] = s;
    }
    __syncthreads();
    float lsum = 0.0f;
    int vcnt = 0;
    for (int a = t; a < AROWS; a += 256) {
        int c = a >> 9, m = a & 511;
        int pc = pcnt[c];
        if (m < counts[c] && pc > 0) {
            float lse = logf(row_sumexp[a]);
            lsum += (row_pos_sum[a] - (float)pc * lse) / (float)pc;
            vcnt += 1;
        }
    }
#pragma unroll
    for (int off = 32; off > 0; off >>= 1) {
        lsum += __shfl_down(lsum, off, 64);
        vcnt += __shfl_down(vcnt, off, 64);
    }
    if ((t & 63) == 0) { sred[t >> 6] = lsum; cred[t >> 6] = vcnt; }
    __syncthreads();
    if (t == 0) {
        float L = sred[0] + sred[1] + sred[2] + sred[3];
        int V = cred[0] + cred[1] + cred[2] + cred[3];
        out[0] = -L / (float)(V > 0 ? V : 1);
    }
}

// ---------------- launch ----------------
extern "C" void kernel_launch(void* const* d_in, const int* in_sizes, int n_in,
                              void* d_out, int out_size, void* d_ws, size_t ws_size,
                              hipStream_t stream) {
    const float* main_proj = (const float*)d_in[0];
    const int*   main_gt   = (const int*)d_in[1];
    const float* aux_proj  = (const float*)d_in[2];
    const int*   aux_gt    = (const int*)d_in[3];
    const float* bank      = (const float*)d_in[4];
    float* out = (float*)d_out;

    char* ws = (char*)d_ws;
    int*   labels      = (int*)ws;   ws += (size_t)NPIX * 4;            // 512 KB
    int*   sel_idx     = (int*)ws;   ws += (size_t)AROWS * 4;           // 40 KB
    int*   counts      = (int*)ws;   ws += 256;                         // 20 ints + pad
    int*   c_valid     = (int*)ws;   ws += (size_t)AROWS * 4;           // 40 KB
    float* row_sumexp  = (float*)ws; ws += (size_t)AROWS * 4;           // 40 KB
    float* row_pos_sum = (float*)ws; ws += (size_t)AROWS * 4;           // 40 KB (contiguous w/ sumexp)
    float* anchors     = (float*)ws; ws += (size_t)AROWS * DIM * 4;     // 10 MB
    float* contras     = (float*)ws; ws += (size_t)AROWS * DIM * 4;     // 10 MB

    k_labels<<<NPIX / 256, 256, 0, stream>>>(main_gt, aux_gt, labels);
    k_select<<<NCLS, 256, 0, stream>>>(labels, sel_idx, counts);
    k_gather<<<AROWS, 256, 0, stream>>>(main_proj, aux_proj, sel_idx, anchors);
    k_bank<<<AROWS, 256, 0, stream>>>(bank, anchors, counts, contras, c_valid);
    hipMemsetAsync(row_sumexp, 0, (size_t)AROWS * 2 * sizeof(float), stream);
    dim3 grid(AROWS / TS, AROWS / TS);
    k_score<<<grid, 256, 0, stream>>>(anchors, contras, c_valid, row_sumexp, row_pos_sum);
    k_final<<<1, 256, 0, stream>>>(row_sumexp, row_pos_sum, c_valid, counts, out);
}

// Round 2
// 328.351 us; speedup vs baseline: 2.5365x; 2.5365x over previous
//
#include <hip/hip_runtime.h>
#include <cstdint>
#include <math.h>

#define NCLS  20
#define MSZ   512
#define DIM   256
#define HW    16384      // 128*128
#define NPIX  131072     // 4 * 2 * 16384
#define AROWS 10240      // NCLS * MSZ
#define TEMP_INV 10.0f

typedef __attribute__((ext_vector_type(8))) short bf16x8;
typedef __attribute__((ext_vector_type(4))) float f32x4;

// fp32 -> bf16 (RNE), no NaN handling needed (data is finite)
__device__ __forceinline__ short f2bf(float f) {
    unsigned u = __float_as_uint(f);
    unsigned r = (u + 0x7FFFu + ((u >> 16) & 1u)) >> 16;
    return (short)r;
}
__device__ __forceinline__ float bf2f(short s) {
    return __uint_as_float(((unsigned)(unsigned short)s) << 16);
}

// async global->LDS, 16B per lane, wave-uniform LDS base (CK-style casts)
__device__ __forceinline__ void gld16(const void* g, void* l) {
    __builtin_amdgcn_global_load_lds(
        (const __attribute__((address_space(1))) unsigned int*)(uintptr_t)g,
        (__attribute__((address_space(3))) unsigned int*)(unsigned int)(uintptr_t)l,
        16, 0, 0);
}

// ---------------- K1: labels from nearest-resized gt ----------------
__global__ __launch_bounds__(256) void k_labels(const int* __restrict__ mg,
                                                const int* __restrict__ ag,
                                                int* __restrict__ labels) {
    int n = blockIdx.x * 256 + threadIdx.x;
    int b = n >> 15;
    int r = n & 32767;
    const int* g = (r < HW) ? mg : ag;
    int p = (r < HW) ? r : (r - HW);
    int h = p >> 7, w = p & 127;
    int lab = g[(((size_t)b * 512) + (size_t)(h << 2)) * 512 + (size_t)(w << 2)];
    if (lab == 255) lab = -1;
    else if (lab == 254) lab = NCLS - 1;
    labels[n] = lab;
}

// ---------------- K2: ordered per-class selection ----------------
__global__ __launch_bounds__(256) void k_select(const int* __restrict__ labels,
                                                int* __restrict__ sel_idx,
                                                int* __restrict__ counts) {
    int c = blockIdx.x;
    int t = threadIdx.x;
    int lane = t & 63, wv = t >> 6;
    __shared__ int wcnt[4];
    int base = 0;
    for (int chunk = 0; chunk < NPIX; chunk += 256) {
        int n = chunk + t;
        bool match = (labels[n] == c);
        unsigned long long mask = __ballot(match);
        if (lane == 0) wcnt[wv] = __popcll(mask);
        __syncthreads();
        int prefix = 0;
#pragma unroll
        for (int i = 0; i < 4; ++i) if (i < wv) prefix += wcnt[i];
        int tot = wcnt[0] + wcnt[1] + wcnt[2] + wcnt[3];
        int rank = base + prefix + __popcll(mask & ((1ull << lane) - 1ull));
        if (match && rank < MSZ) sel_idx[c * MSZ + rank] = n;
        base += tot;
        __syncthreads();
        if (base >= MSZ) break;
    }
    if (t == 0) counts[c] = base;
    for (int r = base + t; r < MSZ; r += 256) sel_idx[c * MSZ + r] = 0;
}

__device__ __forceinline__ float blockReduceSum256(float v, float* sh4) {
    int t = threadIdx.x;
#pragma unroll
    for (int off = 32; off > 0; off >>= 1) v += __shfl_down(v, off, 64);
    if ((t & 63) == 0) sh4[t >> 6] = v;
    __syncthreads();
    float tot = sh4[0] + sh4[1] + sh4[2] + sh4[3];
    __syncthreads();
    return tot;
}

// ---------------- K3: gather + L2-normalize -> bf16 anchors ----------------
__global__ __launch_bounds__(256) void k_gather(const float* __restrict__ mainp,
                                                const float* __restrict__ auxp,
                                                const int* __restrict__ sel_idx,
                                                short* __restrict__ anchorsB) {
    __shared__ float sh4[4];
    int a = blockIdx.x;
    int t = threadIdx.x;
    int n = sel_idx[a];
    int b = n >> 15, r = n & 32767;
    const float* src = (r < HW) ? mainp : auxp;
    int p = (r < HW) ? r : (r - HW);
    float x = src[(size_t)b * DIM * HW + (size_t)t * HW + (size_t)p];
    float ss = blockReduceSum256(x * x, sh4);
    float scale = 1.0f / fmaxf(sqrtf(ss), 1e-12f);
    anchorsB[(size_t)a * DIM + t] = f2bf(x * scale);
}

// ---------------- K4: momentum bank update + renorm -> bf16 contras ----------------
__global__ __launch_bounds__(256) void k_bank(const float* __restrict__ bank,
                                              const short* __restrict__ anchorsB,
                                              const int* __restrict__ counts,
                                              short* __restrict__ contrasB,
                                              int* __restrict__ c_valid) {
    __shared__ float sh4[4];
    int a = blockIdx.x;
    int t = threadIdx.x;
    int c = a >> 9, m = a & 511;
    size_t idx = (size_t)a * DIM + t;
    float bv = bank[idx];
    bool upd = m < counts[c];
    float u = upd ? (0.999f * bv + 0.001f * bf2f(anchorsB[idx])) : bv;
    float ss = blockReduceSum256(u * u, sh4);
    float nrm = sqrtf(ss);
    float outv = upd ? (u / fmaxf(nrm, 1e-12f)) : bv;
    contrasB[idx] = f2bf(outv);
    if (t == 0) c_valid[a] = (nrm > 0.0f) ? 1 : 0;
}

// ---------------- K5: bf16 MFMA scores + fused softmax statistics ----------------
// 128x128 tile / block; 4 waves in 2x2; each wave 64x64 via 4x4 mfma 16x16x32.
#define TS 128
#define BK 32
__global__ __launch_bounds__(256) void k_score(const short* __restrict__ A,
                                               const short* __restrict__ Bc,
                                               const int* __restrict__ c_valid,
                                               float* __restrict__ row_sumexp,
                                               float* __restrict__ row_pos_sum) {
    __shared__ short As[TS * BK];
    __shared__ short Bs[TS * BK];
    int t = threadIdx.x;
    int lane = t & 63;
    int wv = t >> 6;              // wave 0..3
    int wr = wv >> 1, wc = wv & 1;
    int row0 = blockIdx.x * TS, col0 = blockIdx.y * TS;

    f32x4 acc[4][4] = {};

    int lrow = lane >> 2;         // 0..15 (staging row within 16-row group)
    int lseg = lane & 3;          // 0..3  (16B segment within 64B row)
    int qr = lane >> 4;           // 0..3  (MFMA quad)
    int qc = lane & 15;           // 0..15

    const short* Abase = A  + (size_t)(row0 + wv * 32) * DIM;
    const short* Bbase = Bc + (size_t)(col0 + wv * 32) * DIM;
    short* AsW = &As[(wv * 32) * BK];
    short* BsW = &Bs[(wv * 32) * BK];

    for (int k0 = 0; k0 < DIM; k0 += BK) {
        __syncthreads();   // previous tile's reads done before overwrite
#pragma unroll
        for (int g = 0; g < 2; ++g) {
            gld16(Abase + (size_t)(g * 16 + lrow) * DIM + k0 + lseg * 8, AsW + (g * 16) * BK);
            gld16(Bbase + (size_t)(g * 16 + lrow) * DIM + k0 + lseg * 8, BsW + (g * 16) * BK);
        }
        asm volatile("s_waitcnt vmcnt(0)" ::: "memory");
        __syncthreads();

        bf16x8 af[4], bf[4];
#pragma unroll
        for (int i = 0; i < 4; ++i)
            af[i] = *(const bf16x8*)&As[(wr * 64 + i * 16 + qc) * BK + qr * 8];
#pragma unroll
        for (int j = 0; j < 4; ++j)
            bf[j] = *(const bf16x8*)&Bs[(wc * 64 + j * 16 + qc) * BK + qr * 8];
#pragma unroll
        for (int i = 0; i < 4; ++i)
#pragma unroll
            for (int j = 0; j < 4; ++j)
                acc[i][j] = __builtin_amdgcn_mfma_f32_16x16x32_bf16(af[i], bf[j], acc[i][j], 0, 0, 0);
    }

    // epilogue: per-row sum(exp(s)) over valid cols; sum(s) when same-class tile
    bool same = (row0 >> 9) == (col0 >> 9);   // class blocks are 512 wide, TS|512
    int cvi[4];
#pragma unroll
    for (int j = 0; j < 4; ++j) cvi[j] = c_valid[col0 + wc * 64 + j * 16 + qc];

#pragma unroll
    for (int i = 0; i < 4; ++i) {
#pragma unroll
        for (int r = 0; r < 4; ++r) {
            float e = 0.0f, p = 0.0f;
#pragma unroll
            for (int j = 0; j < 4; ++j) {
                if (cvi[j]) {
                    float s = acc[i][j][r] * TEMP_INV;   // |s| <= ~10
                    e += __expf(s);
                    p += s;
                }
            }
#pragma unroll
            for (int m = 1; m < 16; m <<= 1) {
                e += __shfl_xor(e, m, 64);
                p += __shfl_xor(p, m, 64);
            }
            if (qc == 0) {
                int row = row0 + wr * 64 + i * 16 + qr * 4 + r;
                atomicAdd(&row_sumexp[row], e);
                if (same) atomicAdd(&row_pos_sum[row], p);
            }
        }
    }
}

// ---------------- K6: final loss ----------------
__global__ __launch_bounds__(256) void k_final(const float* __restrict__ row_sumexp,
                                               const float* __restrict__ row_pos_sum,
                                               const int* __restrict__ c_valid,
                                               const int* __restrict__ counts,
                                               float* __restrict__ out) {
    __shared__ int pcnt[NCLS];
    __shared__ float sred[4];
    __shared__ int cred[4];
    int t = threadIdx.x;
    if (t < NCLS) {
        int s = 0;
        for (int m = 0; m < MSZ; ++m) s += c_valid[t * MSZ + m];
        pcnt[t] = s;
    }
    __syncthreads();
    float lsum = 0.0f;
    int vcnt = 0;
    for (int a = t; a < AROWS; a += 256) {
        int c = a >> 9, m = a & 511;
        int pc = pcnt[c];
        if (m < counts[c] && pc > 0) {
            float lse = logf(row_sumexp[a]);
            lsum += (row_pos_sum[a] - (float)pc * lse) / (float)pc;
            vcnt += 1;
        }
    }
#pragma unroll
    for (int off = 32; off > 0; off >>= 1) {
        lsum += __shfl_down(lsum, off, 64);
        vcnt += __shfl_down(vcnt, off, 64);
    }
    if ((t & 63) == 0) { sred[t >> 6] = lsum; cred[t >> 6] = vcnt; }
    __syncthreads();
    if (t == 0) {
        float L = sred[0] + sred[1] + sred[2] + sred[3];
        int V = cred[0] + cred[1] + cred[2] + cred[3];
        out[0] = -L / (float)(V > 0 ? V : 1);
    }
}

// ---------------- launch ----------------
extern "C" void kernel_launch(void* const* d_in, const int* in_sizes, int n_in,
                              void* d_out, int out_size, void* d_ws, size_t ws_size,
                              hipStream_t stream) {
    const float* main_proj = (const float*)d_in[0];
    const int*   main_gt   = (const int*)d_in[1];
    const float* aux_proj  = (const float*)d_in[2];
    const int*   aux_gt    = (const int*)d_in[3];
    const float* bank      = (const float*)d_in[4];
    float* out = (float*)d_out;

    char* ws = (char*)d_ws;
    int*   labels      = (int*)ws;   ws += (size_t)NPIX * 4;
    int*   sel_idx     = (int*)ws;   ws += (size_t)AROWS * 4;
    int*   counts      = (int*)ws;   ws += 256;
    int*   c_valid     = (int*)ws;   ws += (size_t)AROWS * 4;
    float* row_sumexp  = (float*)ws; ws += (size_t)AROWS * 4;
    float* row_pos_sum = (float*)ws; ws += (size_t)AROWS * 4;   // contiguous with sumexp
    short* anchorsB    = (short*)ws; ws += (size_t)AROWS * DIM * 2;
    short* contrasB    = (short*)ws; ws += (size_t)AROWS * DIM * 2;

    k_labels<<<NPIX / 256, 256, 0, stream>>>(main_gt, aux_gt, labels);
    k_select<<<NCLS, 256, 0, stream>>>(labels, sel_idx, counts);
    k_gather<<<AROWS, 256, 0, stream>>>(main_proj, aux_proj, sel_idx, anchorsB);
    k_bank<<<AROWS, 256, 0, stream>>>(bank, anchorsB, counts, contrasB, c_valid);
    hipMemsetAsync(row_sumexp, 0, (size_t)AROWS * 2 * sizeof(float), stream);
    dim3 grid(AROWS / TS, AROWS / TS);
    k_score<<<grid, 256, 0, stream>>>(anchorsB, contrasB, c_valid, row_sumexp, row_pos_sum);
    k_final<<<1, 256, 0, stream>>>(row_sumexp, row_pos_sum, c_valid, counts, out);
}